// Round 23
// baseline (108.984 us; speedup 1.0000x reference)
//
#include <hip/hip_runtime.h>
#include <math.h>

// Problem constants (from reference)
constexpr int B_  = 16;
constexpr int LQ_ = 1024;
constexpr int LK_ = 4096;
constexpr int D_  = 256;
constexpr float HALF_BW_F = 64.0f;         // 128 // 2
constexpr float SCALE = 0.0625f;           // (D^-0.25)^2 = 1/sqrt(256)

typedef float  fx4    __attribute__((ext_vector_type(4)));
typedef short  bf16x8 __attribute__((ext_vector_type(8)));
typedef float  f32x4v __attribute__((ext_vector_type(4)));

constexpr int ROWS_PER_UNIT = 16;          // one MFMA M-tile per unit
constexpr int NUNIT = (B_ * LQ_) / ROWS_PER_UNIT;  // 1024 units
constexpr int NXCD  = 8;
constexpr int UNIT_PER_XCD = NUNIT / NXCD; // 128
constexpr int KSPAN = 192;                 // unit key span <= 15*4+129 = 189
constexpr int TPW   = 3;                   // key tiles per wave (12 / 4)

__device__ __forceinline__ unsigned short f2bf(float f) {
    unsigned int u = __float_as_uint(f);
    return (unsigned short)((u + 0x7FFFu + ((u >> 16) & 1u)) >> 16);  // RNE
}
__device__ __forceinline__ bf16x8 pack8(float4 a, float4 b) {
    bf16x8 r;
    r[0] = (short)f2bf(a.x); r[1] = (short)f2bf(a.y);
    r[2] = (short)f2bf(a.z); r[3] = (short)f2bf(a.w);
    r[4] = (short)f2bf(b.x); r[5] = (short)f2bf(b.y);
    r[6] = (short)f2bf(b.z); r[7] = (short)f2bf(b.w);
    return r;
}
__device__ __forceinline__ float wave_max(float v) {
    #pragma unroll
    for (int off = 32; off > 0; off >>= 1)
        v = fmaxf(v, __shfl_xor(v, off, 64));
    return v;
}
__device__ __forceinline__ float wave_sum(float v) {
    #pragma unroll
    for (int off = 32; off > 0; off >>= 1)
        v += __shfl_xor(v, off, 64);
    return v;
}

// Best-of-both merge (R16 specialization x R21 cooperative MFMA, NT stores
// confirmed best by R22 A/B):
//   fill blocks (1024): zero all non-band stripes + V copy = 363 MB store
//     pump at the R13-proven rate, NT.
//   compute blocks (1024): 4-wave cooperative MFMA scores (3 tiles/wave,
//     one barrier), per-wave softmax, then ONLY the <=2 band stripes per
//     row (28 MB) - near-pure read/compute, overlapping the fill drain.
// Types alternate per 8-block group so both cover all 8 XCDs; partner
// blocks are dispatch-adjacent -> same XCD L2. Address partition exact.
__global__ __launch_bounds__(256, 4) void fused_kernel(
    const float* __restrict__ Q, const float* __restrict__ K,
    const float* __restrict__ V,
    const int* __restrict__ qlen, const int* __restrict__ klen,
    float* __restrict__ Wout, float* __restrict__ Vout)
{
    const int Bid  = blockIdx.x;
    const int xcd  = Bid & 7;
    const int type = (Bid >> 3) & 1;
    const int unit = xcd * UNIT_PER_XCD + (Bid >> 4);
    const int tid  = threadIdx.x;
    const int lane = tid & 63;
    const int wave = tid >> 6;
    const int row0 = unit * ROWS_PER_UNIT;
    const int b    = row0 >> 10;
    const int qi0  = row0 & (LQ_ - 1);

    const int   key_len = klen[b];
    const float slope   = (float)key_len / (float)qlen[b];   // fp32 div (ref)

    if (type == 1) {
        // ================= FILL BLOCK: pure store pump (R16) =============
        {   // V copy: 16 rows, 4 per wave
            const float* vs = V    + (size_t)(row0 + wave * 4) * 1024;
            float*       vd = Vout + (size_t)(row0 + wave * 4) * 1024;
            #pragma unroll
            for (int it = 0; it < 16; ++it) {
                const int o = (it * 64 + lane) * 4;
                fx4 t = __builtin_nontemporal_load((const fx4*)(vs + o));
                __builtin_nontemporal_store(t, (fx4*)(vd + o));
            }
        }
        const fx4 z4 = {0.f, 0.f, 0.f, 0.f};
        #pragma unroll
        for (int r = 0; r < 4; ++r) {
            const int rg = wave * 4 + r;
            const float center = (float)(qi0 + rg) * slope;
            int lo = (int)ceilf(center - HALF_BW_F); if (lo < 0) lo = 0;
            int hi = (int)floorf(center + HALF_BW_F); if (hi > key_len - 1) hi = key_len - 1;
            const int s_lo = lo >> 8, s_hi = hi >> 8;
            float* base = Wout + (size_t)(row0 + rg) * LK_;
            #pragma unroll
            for (int j = 0; j < 16; ++j) {
                if (j < s_lo || j > s_hi)
                    __builtin_nontemporal_store(z4, (fx4*)(base + (j * 64 + lane) * 4));
            }
        }
        return;
    }

    // ================= COMPUTE BLOCK: cooperative MFMA (R21) =============
    __shared__ float s_sc[ROWS_PER_UNIT][KSPAN];   // 12 KB

    // unit-uniform key band (union over the 16 rows)
    int lo_w = (int)ceilf((float)qi0 * slope - HALF_BW_F);
    if (lo_w < 0) lo_w = 0;
    int hi_w = (int)floorf((float)(qi0 + 15) * slope + HALF_BW_F);
    if (hi_w > key_len - 1) hi_w = key_len - 1;
    const int nt = (hi_w - lo_w) / 16 + 1;           // <= 12

    const int col = lane & 15;             // A: q-row / B: key-within-tile
    const int kg  = lane >> 4;             // K-chunk sub-index

    // ---- Q A-fragments: lane holds Q[qi0+col][kc*32 + kg*8 + 0..7] ----
    const float* qb = Q + ((size_t)b * LQ_ + qi0 + col) * D_ + kg * 8;
    bf16x8 qf[8];
    #pragma unroll
    for (int kc = 0; kc < 8; ++kc) {
        const float4 u = *(const float4*)(qb + kc * 32);
        const float4 v = *(const float4*)(qb + kc * 32 + 4);
        qf[kc] = pack8(u, v);
    }

    // ---- scores: this wave's tiles t = wave + 4*s, s = 0..2 ----
    const float* kb = K + (size_t)b * LK_ * D_ + kg * 8;
    #pragma unroll
    for (int s = 0; s < TPW; ++s) {
        const int t = wave + 4 * s;
        if (t < nt) {                                // wave-uniform guard
            const int key  = lo_w + t * 16 + col;
            const int keyc = (key <= hi_w) ? key : hi_w;   // clamp: in-batch
            const float* kp = kb + (size_t)keyc * D_;
            float4 u[8], w[8];
            #pragma unroll
            for (int kc = 0; kc < 8; ++kc) {
                u[kc] = *(const float4*)(kp + kc * 32);
                w[kc] = *(const float4*)(kp + kc * 32 + 4);
            }
            f32x4v acc = (f32x4v){0.f, 0.f, 0.f, 0.f};
            #pragma unroll
            for (int kc = 0; kc < 8; ++kc) {
                const bf16x8 kf = pack8(u[kc], w[kc]);
                acc = __builtin_amdgcn_mfma_f32_16x16x32_bf16(qf[kc], kf, acc, 0, 0, 0);
            }
            // C/D layout [m89]: col=lane&15, row=(lane>>4)*4+reg
            #pragma unroll
            for (int r = 0; r < 4; ++r)
                s_sc[kg * 4 + r][t * 16 + col] = acc[r] * SCALE;
        }
    }
    __syncthreads();   // all tiles' raw scores visible to all waves

    // ---- softmax + band-stripe stores: wave owns rows wave*4..wave*4+3 ----
    #pragma unroll
    for (int r = 0; r < 4; ++r) {
        const int rg = wave * 4 + r;
        const float center = (float)(qi0 + rg) * slope;
        int klo = (int)ceilf(center - HALF_BW_F); if (klo < 0) klo = 0;
        int khi = (int)floorf(center + HALF_BW_F); if (khi > key_len - 1) khi = key_len - 1;

        // 3 values/lane over the 192-slot union span, masked by row band
        float v0, v1, v2;
        {
            const int i0 = lane, i1 = lane + 64, i2 = lane + 128;
            const int c0 = lo_w + i0, c1 = lo_w + i1, c2 = lo_w + i2;
            v0 = (c0 >= klo && c0 <= khi) ? s_sc[rg][i0] : -INFINITY;
            v1 = (c1 >= klo && c1 <= khi) ? s_sc[rg][i1] : -INFINITY;
            v2 = (c2 >= klo && c2 <= khi) ? s_sc[rg][i2] : -INFINITY;
        }
        const float mx = wave_max(fmaxf(fmaxf(v0, v1), v2));
        const float e0 = __expf(v0 - mx);   // exp(-inf)=0 for masked slots
        const float e1 = __expf(v1 - mx);
        const float e2 = __expf(v2 - mx);
        const float ssum = wave_sum(e0 + e1 + e2);
        const float inv = 1.0f / ssum;
        s_sc[rg][lane]       = e0 * inv;    // masked slots become 0
        s_sc[rg][lane + 64]  = e1 * inv;
        s_sc[rg][lane + 128] = e2 * inv;
        // same-wave LDS write->read is in-order: store directly

        const int s_lo = klo >> 8, s_hi = khi >> 8;
        float* base = Wout + (size_t)(row0 + rg) * LK_;
        const float* sr = &s_sc[rg][0];              // indexed by key - lo_w
        for (int j = s_lo; j <= s_hi; ++j) {         // <=2 iterations
            const int c0 = (j * 64 + lane) * 4;
            float w[4] = {0.f, 0.f, 0.f, 0.f};
            if (c0 + 3 >= klo && c0 <= khi) {
                #pragma unroll
                for (int i = 0; i < 4; ++i) {
                    const int c = c0 + i;
                    if (c >= klo && c <= khi) w[i] = sr[c - lo_w];
                }
            }
            fx4 w4; w4.x = w[0]; w4.y = w[1]; w4.z = w[2]; w4.w = w[3];
            __builtin_nontemporal_store(w4, (fx4*)(base + c0));
        }
    }
}

extern "C" void kernel_launch(void* const* d_in, const int* in_sizes, int n_in,
                              void* d_out, int out_size, void* d_ws, size_t ws_size,
                              hipStream_t stream) {
    // inputs (setup_inputs order): query, key, value, mask, query_lengths, key_lengths
    const float* Q    = (const float*)d_in[0];
    const float* K    = (const float*)d_in[1];
    const float* V    = (const float*)d_in[2];
    const int*   qlen = (const int*)d_in[4];
    const int*   klen = (const int*)d_in[5];

    float* Wout = (float*)d_out;
    const size_t W_ELEMS = (size_t)B_ * LQ_ * LK_;        // 67,108,864
    float* Vout = Wout + W_ELEMS;

    fused_kernel<<<dim3(2 * NUNIT), dim3(256), 0, stream>>>(
        Q, K, V, qlen, klen, Wout, Vout);
}

// Round 24
// 108.911 us; speedup vs baseline: 1.0007x; 1.0007x over previous
//
#include <hip/hip_runtime.h>
#include <math.h>

// Problem constants (from reference)
constexpr int B_  = 16;
constexpr int LQ_ = 1024;
constexpr int LK_ = 4096;
constexpr int D_  = 256;
constexpr float HALF_BW_F = 64.0f;         // 128 // 2
constexpr float SCALE = 0.0625f;           // (D^-0.25)^2 = 1/sqrt(256)

// native clang vector for nontemporal builtins (HIP_vector_type is rejected)
typedef float fx4 __attribute__((ext_vector_type(4)));

// softmax covers 9*16 = 144 slots; pad to 168 (168 % 32 == 8 -> the 4
// per-row arrays start on different banks)
constexpr int NB_PAD = 168;
constexpr int ROWS_PER_BLK = 16;                 // 4 waves x 4 rows
constexpr int NUNIT = (B_ * LQ_) / ROWS_PER_BLK; // 1024 row-units
constexpr int NXCD = 8;
constexpr int UNIT_PER_XCD = NUNIT / NXCD;       // 128

// DPP row_shr:N — lane i receives from lane i-N (toward higher lanes) within
// the 16-lane DPP row; out-of-range sources read 0 (bound_ctrl=1). After
// shr8,shr4,shr2,shr1 the complete 16-lane sum is in the row's last lane
// (l==15).
template <int CTRL>
__device__ __forceinline__ float dpp_add(float v) {
    int x = __builtin_amdgcn_update_dpp(0, __float_as_int(v), CTRL, 0xF, 0xF, true);
    return v + __int_as_float(x);
}
__device__ __forceinline__ float dpp_reduce16(float v) {
    v = dpp_add<0x118>(v); v = dpp_add<0x114>(v);
    v = dpp_add<0x112>(v); v = dpp_add<0x111>(v);
    return v;   // complete sum in l==15
}

// reductions within a 16-lane group (xor offsets stay inside the group)
__device__ __forceinline__ float grp16_max(float v) {
    #pragma unroll
    for (int off = 8; off > 0; off >>= 1)
        v = fmaxf(v, __shfl_xor(v, off, 64));
    return v;
}
__device__ __forceinline__ float grp16_sum(float v) {
    #pragma unroll
    for (int off = 8; off > 0; off >>= 1)
        v += __shfl_xor(v, off, 64);
    return v;
}

// R16 champion structure (96.4 us), ONE knob: 4 keys per 16-lane group per
// iteration (16 keys/wave/iter, stride 16). MLP is the only lever with a
// consistent positive slope across 23 rounds (4-key: 100.0 -> 8-key: 96.4);
// this pushes 16 loads/iter back-to-back (x unroll 2 -> up to 32 in
// flight). Everything else byte-identical to R16.
__global__ __launch_bounds__(256, 2) void stripe_attn_kernel(
    const float* __restrict__ Q, const float* __restrict__ K,
    const float* __restrict__ V,
    const int* __restrict__ qlen, const int* __restrict__ klen,
    float* __restrict__ Wout, float* __restrict__ Vout)
{
    const int Bid  = blockIdx.x;
    const int xcd  = Bid & 7;
    const int type = (Bid >> 3) & 1;
    const int rb   = xcd * UNIT_PER_XCD + (Bid >> 4);
    const int tid  = threadIdx.x;
    const int lane = tid & 63;
    const int wave = tid >> 6;
    const int row0 = rb * ROWS_PER_BLK + wave * 4;   // first of this wave's 4 rows
    const int b    = row0 >> 10;           // same batch for all 16 unit rows
    const int qi0  = row0 & (LQ_ - 1);

    __shared__ float s_sc[4][4 * NB_PAD];  // [wave][row*NB_PAD + slot]

    const int   key_len = klen[b];
    const float slope   = (float)key_len / (float)qlen[b];   // fp32 div (ref)

    // per-row integer band (exact fp32 arithmetic as reference)
    int k_lo[4], k_hi[4];                  // only static-indexed below
    #pragma unroll
    for (int r = 0; r < 4; ++r) {
        const float center = (float)(qi0 + r) * slope;
        int lo = (int)ceilf(center - HALF_BW_F); if (lo < 0) lo = 0;
        int hi = (int)floorf(center + HALF_BW_F); if (hi > key_len - 1) hi = key_len - 1;
        k_lo[r] = lo; k_hi[r] = hi;
    }

    if (type == 1) {
        // ================= FILL BLOCK: pure store pump =================
        const float* vs = V    + (size_t)row0 * 1024;
        float*       vd = Vout + (size_t)row0 * 1024;
        #pragma unroll
        for (int it = 0; it < 16; ++it) {
            const int o = (it * 64 + lane) * 4;
            fx4 t = __builtin_nontemporal_load((const fx4*)(vs + o));
            __builtin_nontemporal_store(t, (fx4*)(vd + o));
        }
        const fx4 z4 = {0.f, 0.f, 0.f, 0.f};
        #pragma unroll
        for (int r = 0; r < 4; ++r) {
            const int s_lo = k_lo[r] >> 8, s_hi = k_hi[r] >> 8;
            float* base = Wout + (size_t)(row0 + r) * LK_;
            #pragma unroll
            for (int j = 0; j < 16; ++j) {
                if (j < s_lo || j > s_hi)
                    __builtin_nontemporal_store(z4, (fx4*)(base + (j * 64 + lane) * 4));
            }
        }
        return;
    }

    // ================= COMPUTE BLOCK =================
    const int g   = lane >> 4;             // group 0..3
    const int l   = lane & 15;             // D-chunk 0..15 (16 floats each)
    const int lo0 = k_lo[0], hi3 = k_hi[3];    // union band (nondecreasing)

    // ---- Q staging: 4 rows x 4 float4 (lane l covers floats l*16..l*16+15)
    const float* qbase = Q + ((size_t)b * LQ_ + qi0) * D_;
    float4 q0[4], q1[4], q2[4], q3[4];
    #pragma unroll
    for (int m = 0; m < 4; ++m) {
        q0[m] = *(const float4*)(qbase + 0 * D_ + l * 16 + m * 4);
        q1[m] = *(const float4*)(qbase + 1 * D_ + l * 16 + m * 4);
        q2[m] = *(const float4*)(qbase + 2 * D_ + l * 16 + m * 4);
        q3[m] = *(const float4*)(qbase + 3 * D_ + l * 16 + m * 4);
    }

    // ---- scores: 16 keys/iter (4 per 16-lane group), each serves 4 rows ---
    const float* kbase = K + (size_t)b * LK_ * D_;
    float* sw = s_sc[wave];
    #pragma unroll 2
    for (int kk0 = lo0; kk0 <= hi3; kk0 += 16) {
        const int keyA = kk0 + g,      keyB = kk0 + g + 4;
        const int keyC = kk0 + g + 8,  keyD = kk0 + g + 12;
        const int keyAc = (keyA <= hi3) ? keyA : hi3;  // clamp: safe, in-batch
        const int keyBc = (keyB <= hi3) ? keyB : hi3;
        const int keyCc = (keyC <= hi3) ? keyC : hi3;
        const int keyDc = (keyD <= hi3) ? keyD : hi3;
        const float* kpA = kbase + (size_t)keyAc * D_ + l * 16;
        const float* kpB = kbase + (size_t)keyBc * D_ + l * 16;
        const float* kpC = kbase + (size_t)keyCc * D_ + l * 16;
        const float* kpD = kbase + (size_t)keyDc * D_ + l * 16;
        float4 kfA[4], kfB[4], kfC[4], kfD[4];
        #pragma unroll
        for (int m = 0; m < 4; ++m) kfA[m] = *(const float4*)(kpA + m * 4);
        #pragma unroll
        for (int m = 0; m < 4; ++m) kfB[m] = *(const float4*)(kpB + m * 4);
        #pragma unroll
        for (int m = 0; m < 4; ++m) kfC[m] = *(const float4*)(kpC + m * 4);
        #pragma unroll
        for (int m = 0; m < 4; ++m) kfD[m] = *(const float4*)(kpD + m * 4);

        float a0 = 0.f, a1 = 0.f, a2 = 0.f, a3 = 0.f;
        float b0 = 0.f, b1 = 0.f, b2 = 0.f, b3 = 0.f;
        float c0 = 0.f, c1 = 0.f, c2 = 0.f, c3 = 0.f;
        float d0 = 0.f, d1 = 0.f, d2 = 0.f, d3 = 0.f;
        #pragma unroll
        for (int m = 0; m < 4; ++m) {
            a0 += q0[m].x*kfA[m].x + q0[m].y*kfA[m].y + q0[m].z*kfA[m].z + q0[m].w*kfA[m].w;
            a1 += q1[m].x*kfA[m].x + q1[m].y*kfA[m].y + q1[m].z*kfA[m].z + q1[m].w*kfA[m].w;
            a2 += q2[m].x*kfA[m].x + q2[m].y*kfA[m].y + q2[m].z*kfA[m].z + q2[m].w*kfA[m].w;
            a3 += q3[m].x*kfA[m].x + q3[m].y*kfA[m].y + q3[m].z*kfA[m].z + q3[m].w*kfA[m].w;
            b0 += q0[m].x*kfB[m].x + q0[m].y*kfB[m].y + q0[m].z*kfB[m].z + q0[m].w*kfB[m].w;
            b1 += q1[m].x*kfB[m].x + q1[m].y*kfB[m].y + q1[m].z*kfB[m].z + q1[m].w*kfB[m].w;
            b2 += q2[m].x*kfB[m].x + q2[m].y*kfB[m].y + q2[m].z*kfB[m].z + q2[m].w*kfB[m].w;
            b3 += q3[m].x*kfB[m].x + q3[m].y*kfB[m].y + q3[m].z*kfB[m].z + q3[m].w*kfB[m].w;
            c0 += q0[m].x*kfC[m].x + q0[m].y*kfC[m].y + q0[m].z*kfC[m].z + q0[m].w*kfC[m].w;
            c1 += q1[m].x*kfC[m].x + q1[m].y*kfC[m].y + q1[m].z*kfC[m].z + q1[m].w*kfC[m].w;
            c2 += q2[m].x*kfC[m].x + q2[m].y*kfC[m].y + q2[m].z*kfC[m].z + q2[m].w*kfC[m].w;
            c3 += q3[m].x*kfC[m].x + q3[m].y*kfC[m].y + q3[m].z*kfC[m].z + q3[m].w*kfC[m].w;
            d0 += q0[m].x*kfD[m].x + q0[m].y*kfD[m].y + q0[m].z*kfD[m].z + q0[m].w*kfD[m].w;
            d1 += q1[m].x*kfD[m].x + q1[m].y*kfD[m].y + q1[m].z*kfD[m].z + q1[m].w*kfD[m].w;
            d2 += q2[m].x*kfD[m].x + q2[m].y*kfD[m].y + q2[m].z*kfD[m].z + q2[m].w*kfD[m].w;
            d3 += q3[m].x*kfD[m].x + q3[m].y*kfD[m].y + q3[m].z*kfD[m].z + q3[m].w*kfD[m].w;
        }
        a0 = dpp_reduce16(a0); a1 = dpp_reduce16(a1);
        a2 = dpp_reduce16(a2); a3 = dpp_reduce16(a3);
        b0 = dpp_reduce16(b0); b1 = dpp_reduce16(b1);
        b2 = dpp_reduce16(b2); b3 = dpp_reduce16(b3);
        c0 = dpp_reduce16(c0); c1 = dpp_reduce16(c1);
        c2 = dpp_reduce16(c2); c3 = dpp_reduce16(c3);
        d0 = dpp_reduce16(d0); d1 = dpp_reduce16(d1);
        d2 = dpp_reduce16(d2); d3 = dpp_reduce16(d3);
        if (l == 15) {   // unclamped keys in conditions -> clamped dups never store
            if (keyA >= k_lo[0] && keyA <= k_hi[0]) sw[0*NB_PAD + keyA - k_lo[0]] = a0 * SCALE;
            if (keyA >= k_lo[1] && keyA <= k_hi[1]) sw[1*NB_PAD + keyA - k_lo[1]] = a1 * SCALE;
            if (keyA >= k_lo[2] && keyA <= k_hi[2]) sw[2*NB_PAD + keyA - k_lo[2]] = a2 * SCALE;
            if (keyA >= k_lo[3] && keyA <= k_hi[3]) sw[3*NB_PAD + keyA - k_lo[3]] = a3 * SCALE;
            if (keyB >= k_lo[0] && keyB <= k_hi[0]) sw[0*NB_PAD + keyB - k_lo[0]] = b0 * SCALE;
            if (keyB >= k_lo[1] && keyB <= k_hi[1]) sw[1*NB_PAD + keyB - k_lo[1]] = b1 * SCALE;
            if (keyB >= k_lo[2] && keyB <= k_hi[2]) sw[2*NB_PAD + keyB - k_lo[2]] = b2 * SCALE;
            if (keyB >= k_lo[3] && keyB <= k_hi[3]) sw[3*NB_PAD + keyB - k_lo[3]] = b3 * SCALE;
            if (keyC >= k_lo[0] && keyC <= k_hi[0]) sw[0*NB_PAD + keyC - k_lo[0]] = c0 * SCALE;
            if (keyC >= k_lo[1] && keyC <= k_hi[1]) sw[1*NB_PAD + keyC - k_lo[1]] = c1 * SCALE;
            if (keyC >= k_lo[2] && keyC <= k_hi[2]) sw[2*NB_PAD + keyC - k_lo[2]] = c2 * SCALE;
            if (keyC >= k_lo[3] && keyC <= k_hi[3]) sw[3*NB_PAD + keyC - k_lo[3]] = c3 * SCALE;
            if (keyD >= k_lo[0] && keyD <= k_hi[0]) sw[0*NB_PAD + keyD - k_lo[0]] = d0 * SCALE;
            if (keyD >= k_lo[1] && keyD <= k_hi[1]) sw[1*NB_PAD + keyD - k_lo[1]] = d1 * SCALE;
            if (keyD >= k_lo[2] && keyD <= k_hi[2]) sw[2*NB_PAD + keyD - k_lo[2]] = d2 * SCALE;
            if (keyD >= k_lo[3] && keyD <= k_hi[3]) sw[3*NB_PAD + keyD - k_lo[3]] = d3 * SCALE;
        }
    }

    // ---- softmax: 16-lane group g owns row g (9 values per lane) ----
    // recompute band from scalars (k_lo[g] with runtime g would spill, rule #20)
    const float center_g = (float)(qi0 + g) * slope;
    int klo_g = (int)ceilf(center_g - HALF_BW_F); if (klo_g < 0) klo_g = 0;
    int khi_g = (int)floorf(center_g + HALF_BW_F); if (khi_g > key_len - 1) khi_g = key_len - 1;
    const int nb_g = khi_g - klo_g + 1;    // 65..129
    float* sg = sw + g * NB_PAD;

    float vj[9];
    #pragma unroll
    for (int j = 0; j < 9; ++j) {
        const int idx = l + j * 16;
        vj[j] = (idx < nb_g) ? sg[idx] : -INFINITY;
    }
    float mx = vj[0];
    #pragma unroll
    for (int j = 1; j < 9; ++j) mx = fmaxf(mx, vj[j]);
    mx = grp16_max(mx);

    float ej[9], ssum = 0.f;
    #pragma unroll
    for (int j = 0; j < 9; ++j) { ej[j] = __expf(vj[j] - mx); ssum += ej[j]; }
    ssum = grp16_sum(ssum);
    const float inv = 1.0f / ssum;
    #pragma unroll
    for (int j = 0; j < 9; ++j)
        sg[l + j * 16] = ej[j] * inv;      // padding slots get 0, never read

    // ---- band stripes only (<=2 per row; fill partner wrote the rest) ----
    #pragma unroll
    for (int r = 0; r < 4; ++r) {
        const int klo = k_lo[r], khi = k_hi[r];
        const int s_lo = klo >> 8, s_hi = khi >> 8;
        float* base = Wout + (size_t)(row0 + r) * LK_;
        const float* sr = sw + r * NB_PAD;
        for (int j = s_lo; j <= s_hi; ++j) {           // <=2 iterations
            const int c0 = (j * 64 + lane) * 4;        // column of this float4
            float w[4] = {0.f, 0.f, 0.f, 0.f};
            if (c0 + 3 >= klo && c0 <= khi) {
                #pragma unroll
                for (int i = 0; i < 4; ++i) {
                    const int c = c0 + i;
                    if (c >= klo && c <= khi) w[i] = sr[c - klo];
                }
            }
            fx4 w4; w4.x = w[0]; w4.y = w[1]; w4.z = w[2]; w4.w = w[3];
            __builtin_nontemporal_store(w4, (fx4*)(base + c0));
        }
    }
}

extern "C" void kernel_launch(void* const* d_in, const int* in_sizes, int n_in,
                              void* d_out, int out_size, void* d_ws, size_t ws_size,
                              hipStream_t stream) {
    // inputs (setup_inputs order): query, key, value, mask, query_lengths, key_lengths
    const float* Q    = (const float*)d_in[0];
    const float* K    = (const float*)d_in[1];
    const float* V    = (const float*)d_in[2];
    const int*   qlen = (const int*)d_in[4];
    const int*   klen = (const int*)d_in[5];

    float* Wout = (float*)d_out;
    const size_t W_ELEMS = (size_t)B_ * LQ_ * LK_;        // 67,108,864
    float* Vout = Wout + W_ELEMS;

    stripe_attn_kernel<<<dim3(2 * NUNIT), dim3(256), 0, stream>>>(
        Q, K, V, qlen, klen, Wout, Vout);
}